// Round 4
// baseline (655.305 us; speedup 1.0000x reference)
//
#include <hip/hip_runtime.h>
#include <hip/hip_bf16.h>

#define T_DIM 4096
#define B_DIM 4

typedef unsigned short u16;
typedef __attribute__((ext_vector_type(4))) short s16x4;
typedef __attribute__((ext_vector_type(8))) short short8;
typedef __attribute__((ext_vector_type(8))) __bf16 bf16x8;
typedef __attribute__((ext_vector_type(4))) float f32x4;

static __device__ __forceinline__ u16 f2bf(float f) {
    union { float f; unsigned int u; } v; v.f = f;
    unsigned int u = v.u;
    u += 0x7FFFu + ((u >> 16) & 1u);   // RNE
    return (u16)(u >> 16);
}

static __device__ __forceinline__ f32x4 mfma_k32(short8 a, short8 b, f32x4 c) {
    return __builtin_amdgcn_mfma_f32_16x16x32_bf16(
        __builtin_bit_cast(bf16x8, a), __builtin_bit_cast(bf16x8, b), c, 0, 0, 0);
}
// 16x16x16 bf16 (CDNA3 carry-forward): A,B = 4 bf16 as <4 x i16>
static __device__ __forceinline__ f32x4 mfma_k16(s16x4 a, s16x4 b, f32x4 c) {
    return __builtin_amdgcn_mfma_f32_16x16x16bf16_1k(a, b, c, 0, 0, 0);
}

// ---------------------------------------------------------------------------
// Kernel 0: transpose + convert the three 256x256 fp32 weights to bf16 W^T[n][k]
// ---------------------------------------------------------------------------
__global__ __launch_bounds__(256) void wtrans_kernel(
    const float* __restrict__ Wq, const float* __restrict__ Wk,
    const float* __restrict__ Wv, u16* __restrict__ wT) {
    int idx = blockIdx.x * 256 + threadIdx.x;
    int w   = idx >> 16;
    int rem = idx & 65535;
    int k   = rem >> 8;
    int n   = rem & 255;
    const float* W = (w == 0) ? Wq : (w == 1) ? Wk : Wv;
    wT[w * 65536 + n * 256 + k] = f2bf(W[k * 256 + n]);
}

// ---------------------------------------------------------------------------
// Kernel 1: projection GEMM, 16 rows/block (grid 1024 = 4 blocks/CU).
// All three weights in one pass; X converted once, reused x3.
// ---------------------------------------------------------------------------
__global__ __launch_bounds__(256, 4) void proj_kernel(
    const float* __restrict__ X, const u16* __restrict__ wT,
    u16* __restrict__ q_ws, u16* __restrict__ k_ws, u16* __restrict__ vT_ws) {
    const int r0  = blockIdx.x * 16;
    const int wid = threadIdx.x >> 6, lane = threadIdx.x & 63;
    const int lr  = lane & 15, lg = lane >> 4;

    short8 af[8];
    const float* xrow = X + (size_t)(r0 + lr) * 256 + lg * 8;
#pragma unroll
    for (int kc = 0; kc < 8; ++kc) {
        f32x4 xa = *(const f32x4*)(xrow + kc * 32);
        f32x4 xb = *(const f32x4*)(xrow + kc * 32 + 4);
        union { u16 u[8]; short8 v; } t;
#pragma unroll
        for (int e = 0; e < 4; ++e) { t.u[e] = f2bf(xa[e]); t.u[4 + e] = f2bf(xb[e]); }
        af[kc] = t.v;
    }

    for (int w = 0; w < 3; ++w) {
        f32x4 acc[4];
#pragma unroll
        for (int nf = 0; nf < 4; ++nf) acc[nf] = (f32x4){0.f,0.f,0.f,0.f};
        const u16* wbase = wT + w * 65536 + (size_t)(16 * (4 * wid) + lr) * 256 + lg * 8;
#pragma unroll
        for (int kc = 0; kc < 8; ++kc)
#pragma unroll
            for (int nf = 0; nf < 4; ++nf) {
                short8 bfv = *(const short8*)(wbase + nf * 16 * 256 + kc * 32);
                acc[nf] = mfma_k32(af[kc], bfv, acc[nf]);
            }
#pragma unroll
        for (int nf = 0; nf < 4; ++nf)
#pragma unroll
            for (int r = 0; r < 4; ++r) {
                int rg = r0 + 4 * lg + r;
                int t  = rg >> 2, bb = rg & 3;
                int d  = 16 * (4 * wid + nf) + lr;
                u16 val = f2bf(acc[nf][r]);
                if (w == 0)      q_ws[((size_t)bb * T_DIM + t) * 256 + d] = val;
                else if (w == 1) k_ws[((size_t)bb * T_DIM + t) * 256 + d] = val;
                else             vT_ws[((size_t)bb * 256 + d) * T_DIM + t] = val;
            }
    }
}

// ---------------------------------------------------------------------------
// Kernel 2: fused causal attention, swapped-QK^T layout, NO barriers in the
// j-loop. Block = (b, 16-row query tile), 4 waves; wave wid owns j-columns
// [16*wid, 16*wid+16) of each 64-wide j-tile.
//   QK^T: S^T = mfma(K, Q)  -> lane(lr,lg) holds S[i0+lr][j0+16w+4lg+r], r=0..3
//   attn store: one f32x4 per lane; row sum: lane-local + shfl_xor(16,32)
//   PV: P registers ARE the 16x16x16 A-frag; V^T gives the B-frag (8B loads)
// O partials combined across waves via LDS at the end.
// ---------------------------------------------------------------------------
__global__ __launch_bounds__(256, 3) void attn_kernel(
    const u16* __restrict__ q_ws, const u16* __restrict__ k_ws,
    const u16* __restrict__ vT_ws, float* __restrict__ out) {
    __shared__ float l_sm[16];
    __shared__ float O_sm[16 * 264];   // padded stride 264 floats

    // block -> (b, i_tile): b per XCD pair; heavy tiles dispatched first
    const int blk = blockIdx.x;
    const int xcd = blk & 7, kdx = blk >> 3;
    const int b = xcd >> 1, par = xcd & 1;
    const int i_tile = 2 * (127 - kdx) + par;   // 0..255, heavy-first
    const int i0 = i_tile * 16;

    const int tid = threadIdx.x;
    const int wid = tid >> 6, lane = tid & 63;
    const int lr = lane & 15, lg = lane >> 4;

    float* attnO = out + (size_t)T_DIM * B_DIM * 256 + (size_t)b * T_DIM * T_DIM;
    const int irow = i0 + lr;

    // Q as B-fragment (same per-lane loads as an A-frag of Q rows)
    short8 q8[8];
    {
        const u16* qbase = q_ws + ((size_t)b * T_DIM + irow) * 256 + lg * 8;
#pragma unroll
        for (int kc = 0; kc < 8; ++kc)
            q8[kc] = *(const short8*)(qbase + kc * 32);
    }
    if (tid < 16) l_sm[tid] = 0.f;
    __syncthreads();

    const int numJT = i_tile / 4 + 1;
    const u16* kbase = k_ws + ((size_t)b * T_DIM + 16 * wid + lr) * 256 + lg * 8;

    // ---- sweep 1: row sums of exp(S) ----
    float rs = 0.f;
    for (int jt = 0; jt < numJT; ++jt) {
        const u16* kp = kbase + (size_t)jt * 64 * 256;
        f32x4 a0 = {0.f,0.f,0.f,0.f};
#pragma unroll
        for (int kc = 0; kc < 8; ++kc) {
            short8 kf = *(const short8*)(kp + kc * 32);
            a0 = mfma_k32(kf, q8[kc], a0);
        }
        const int jcol = jt * 64 + 16 * wid + 4 * lg;
#pragma unroll
        for (int r = 0; r < 4; ++r)
            rs += (jcol + r <= irow) ? __expf(a0[r] * 0.0625f) : 0.f;
    }
    rs += __shfl_xor(rs, 16, 64);
    rs += __shfl_xor(rs, 32, 64);
    if (lane < 16) atomicAdd(&l_sm[lr], rs);
    __syncthreads();
    if (tid < 16) l_sm[tid] = 1.0f / l_sm[tid];
    __syncthreads();
    const float inv = l_sm[lr];

    // ---- sweep 2: attn write + PV, barrier-free ----
    f32x4 oacc[16];
#pragma unroll
    for (int nf = 0; nf < 16; ++nf) oacc[nf] = (f32x4){0.f,0.f,0.f,0.f};

    const u16* vbase = vT_ws + ((size_t)b * 256 + lr) * T_DIM;

    for (int jt = 0; jt < numJT; ++jt) {
        const u16* kp = kbase + (size_t)jt * 64 * 256;
        f32x4 a0 = {0.f,0.f,0.f,0.f};
#pragma unroll
        for (int kc = 0; kc < 8; ++kc) {
            short8 kf = *(const short8*)(kp + kc * 32);
            a0 = mfma_k32(kf, q8[kc], a0);
        }
        const int jcol = jt * 64 + 16 * wid + 4 * lg;
        f32x4 p;
#pragma unroll
        for (int r = 0; r < 4; ++r)
            p[r] = (jcol + r <= irow) ? __expf(a0[r] * 0.0625f) * inv : 0.f;
        __builtin_nontemporal_store(p, (f32x4*)(attnO + (size_t)irow * T_DIM + jcol));

        union { u16 u[4]; s16x4 v; } pk;
#pragma unroll
        for (int r = 0; r < 4; ++r) pk.u[r] = f2bf(p[r]);

        const u16* vrow = vbase + jcol;
#pragma unroll
        for (int nf = 0; nf < 16; ++nf) {
            s16x4 vf = *(const s16x4*)(vrow + (size_t)nf * 16 * T_DIM);
            oacc[nf] = mfma_k16(pk.v, vf, oacc[nf]);
        }
    }

    // ---- combine wave-partial O via LDS (sequential waves, no races) ----
    for (int w = 0; w < 4; ++w) {
        if (wid == w) {
#pragma unroll
            for (int nf = 0; nf < 16; ++nf)
#pragma unroll
                for (int r = 0; r < 4; ++r) {
                    int row = 4 * lg + r, d = 16 * nf + lr;
                    if (w == 0) O_sm[row * 264 + d] = oacc[nf][r];
                    else        O_sm[row * 264 + d] += oacc[nf][r];
                }
        }
        __syncthreads();
    }
    // store O -> results[t][b][d]
#pragma unroll
    for (int u = 0; u < 4; ++u) {
        int idx = tid + 256 * u;            // 0..1023
        int row = idx >> 6, c = idx & 63;   // 16 rows x 64 f32x4 chunks
        f32x4 v = *(const f32x4*)(O_sm + row * 264 + c * 4);
        __builtin_nontemporal_store(v, (f32x4*)(out + ((size_t)(i0 + row) * B_DIM + b) * 256 + c * 4));
    }

    // zero-fill strict upper triangle beyond computed tiles
    const int z0 = numJT * 64;
    if (z0 < T_DIM) {
        const int perRow = (T_DIM - z0) >> 2;
        for (int rr = 0; rr < 16; ++rr) {
            f32x4* rowp = (f32x4*)(attnO + (size_t)(i0 + rr) * T_DIM + z0);
            for (int c = tid; c < perRow; c += 256) {
                f32x4 z = {0.f, 0.f, 0.f, 0.f};
                __builtin_nontemporal_store(z, rowp + c);
            }
        }
    }
}

// ---------------------------------------------------------------------------
extern "C" void kernel_launch(void* const* d_in, const int* in_sizes, int n_in,
                              void* d_out, int out_size, void* d_ws, size_t ws_size,
                              hipStream_t stream) {
    (void)in_sizes; (void)n_in; (void)out_size; (void)ws_size;
    const float* X  = (const float*)d_in[0];
    const float* Wq = (const float*)d_in[1];
    const float* Wk = (const float*)d_in[2];
    const float* Wv = (const float*)d_in[3];
    float* out = (float*)d_out;

    char* ws = (char*)d_ws;
    u16* q_ws  = (u16*)(ws);                                  // 8 MB
    u16* k_ws  = (u16*)(ws + (size_t)8  * 1024 * 1024);       // 8 MB
    u16* vT_ws = (u16*)(ws + (size_t)16 * 1024 * 1024);       // 8 MB
    u16* wT    = (u16*)(ws + (size_t)24 * 1024 * 1024);       // 384 KB

    wtrans_kernel<<<dim3(768), dim3(256), 0, stream>>>(Wq, Wk, Wv, wT);
    proj_kernel<<<dim3(1024), dim3(256), 0, stream>>>(X, wT, q_ws, k_ws, vT_ws);
    attn_kernel<<<dim3(1024), dim3(256), 0, stream>>>(q_ws, k_ws, vT_ws, out);
}